// Round 15
// baseline (119.142 us; speedup 1.0000x reference)
//
#include <hip/hip_runtime.h>
#include <stdint.h>

typedef __attribute__((ext_vector_type(8))) __bf16 bf16x8;
typedef __attribute__((ext_vector_type(4))) __bf16 bf16x4;
typedef __attribute__((ext_vector_type(4))) float f32x4;

// barrier WITHOUT vmcnt drain: LDS ops must land, global loads stay in flight
#define LGKM_BAR() do { asm volatile("s_waitcnt lgkmcnt(0)" ::: "memory"); \
                        __builtin_amdgcn_s_barrier(); } while (0)

namespace {
constexpr int N_ = 64, C_ = 512, P_ = 900, K_ = 64;
constexpr int PP = 960;                               // padded P for at/Lq
constexpr size_t TOT_X = (size_t)N_ * C_ * P_;        // 117,964,800 floats
constexpr size_t AT_BYTES = (size_t)N_ * K_ * PP * 2;          // bf16 a' [n][k][960]
constexpr size_t ASUM_OFF = AT_BYTES;                          // f32 [n][k]
constexpr size_t WBR_OFF  = ASUM_OFF + (size_t)N_ * K_ * 4;    // bf16 wbr [oct][k][8]
constexpr size_t SSQ_OFF  = WBR_OFF + (size_t)K_ * C_ * 2;     // f32 ssqq [8][n][1024]
constexpr size_t LQ_OFF   = SSQ_OFF + (size_t)8 * N_ * 1024 * 4; // bf16 Lq [8][n][k][960]
}

// --- prep: wbr[oct][k][j] = bf16(w[k][oct*8+j]) (A-frag-ready layout); zero asum.
__global__ __launch_bounds__(256) void k_prep_w(const float* __restrict__ w,
                                                __bf16* __restrict__ wbr,
                                                float* __restrict__ asum) {
  const int T = blockIdx.x * 256 + threadIdx.x;      // 0..4095
  const int k = T >> 6, oct = T & 63;
  const float4 a = *reinterpret_cast<const float4*>(w + (size_t)k * C_ + oct * 8);
  const float4 b = *reinterpret_cast<const float4*>(w + (size_t)k * C_ + oct * 8 + 4);
  bf16x8 o = { (__bf16)a.x, (__bf16)a.y, (__bf16)a.z, (__bf16)a.w,
               (__bf16)b.x, (__bf16)b.y, (__bf16)b.z, (__bf16)b.w };
  *reinterpret_cast<bf16x8*>(wbr + ((size_t)oct * K_ + k) * 8) = o;
  asum[T] = 0.f;
}

// --- phase 1 (slab footprint = phase2's shape): block (c-slice 64 rows, n) reads
//     ONE contiguous 230KB slab; p is the OUTPUT dim (8 chunks of 128) so acc is
//     16 VGPR/wave, written per chunk -> no spills. Partial logits to Lq bf16,
//     partial ssq to ssqq. 512 thr / 8 waves; wave owns 16 p x all 64 k per chunk.
__global__ __launch_bounds__(512) void k_phase1(const float* __restrict__ x,
                                                const __bf16* __restrict__ wbr,
                                                __bf16* __restrict__ Lq,
                                                float* __restrict__ ssqq) {
  __shared__ __bf16 Xt[2][64][134];    // [buf][c64][p128+pad] stride 134 u16 (67 dw)
  __shared__ bf16x8 Wl[512];           // 8 KB: this slice's W, [oct_local 8][k 64]
  __shared__ float ssq_l[2][132];
  const int cs = blockIdx.x, n = blockIdx.y;
  const int tid = threadIdx.x;
  const int wv  = tid >> 6, l = tid & 63;
  const int l15 = l & 15,  lh = l >> 4;

  // stage W slice: octs cs*8..cs*8+8 -> Wl[oct_local*64 + k]; index = cs*512+tid
  Wl[tid] = reinterpret_cast<const bf16x8*>(wbr)[(size_t)cs * 512 + tid];
  if (tid < 128) { ssq_l[0][tid] = 0.f; ssq_l[1][tid] = 0.f; }

  // staging map: thread covers rows {row0+16i}, p-quad col (fixed)
  const int row0 = tid >> 5;           // 0..15
  const int col  = tid & 31;           // f4-col within 128-p chunk
  const float* xb = x + ((size_t)n * C_ + cs * 64 + row0) * P_ + col * 4;

  float4 ring[2][4];
  auto LOADR = [&](int s, int slot) {
    const bool pv = (s * 128 + col * 4) <= P_ - 4;   // float4 fully in-bounds
    #pragma unroll
    for (int i = 0; i < 4; ++i)
      ring[slot][i] = pv ? *reinterpret_cast<const float4*>(
                               xb + (size_t)i * 16 * P_ + s * 128)
                         : make_float4(0.f, 0.f, 0.f, 0.f);
  };
  auto STORE = [&](int s) {            // convert + LDS + ssq atomics (buf/slot = s&1)
    const int b = s & 1;
    float sqv[4] = {0.f, 0.f, 0.f, 0.f};
    #pragma unroll
    for (int i = 0; i < 4; ++i) {
      const float4 v = ring[b][i];
      sqv[0] = fmaf(v.x, v.x, sqv[0]); sqv[1] = fmaf(v.y, v.y, sqv[1]);
      sqv[2] = fmaf(v.z, v.z, sqv[2]); sqv[3] = fmaf(v.w, v.w, sqv[3]);
      bf16x4 o = { (__bf16)v.x, (__bf16)v.y, (__bf16)v.z, (__bf16)v.w };
      *reinterpret_cast<bf16x4*>(&Xt[b][row0 + 16 * i][col * 4]) = o;
    }
    #pragma unroll
    for (int j = 0; j < 4; ++j) atomicAdd(&ssq_l[b][col * 4 + j], sqv[j]);
  };

  // prologue
  LOADR(0, 0); LOADR(1, 1);
  __syncthreads();                     // ssq_l zero + Wl visible before atomics
  STORE(0);
  LGKM_BAR();

  float* sqo = ssqq + ((size_t)(cs * N_ + n) << 10);
  __bf16* lqo = Lq + (size_t)(cs * N_ + n) * K_ * PP;

  #pragma unroll
  for (int s = 0; s < 8; ++s) {
    if (s + 2 < 8) LOADR(s + 2, s & 1);
    // compute this chunk: contraction over the block's 64 c (2 csteps)
    f32x4 acc[4] = {};
    #pragma unroll
    for (int cstep = 0; cstep < 2; ++cstep) {
      bf16x8 b;
      #pragma unroll
      for (int j = 0; j < 8; ++j)
        b[j] = Xt[s & 1][cstep * 32 + lh * 8 + j][wv * 16 + l15];
      #pragma unroll
      for (int m = 0; m < 4; ++m) {
        bf16x8 a = Wl[(cstep * 4 + lh) * 64 + 16 * m + l15];
        acc[m] = __builtin_amdgcn_mfma_f32_16x16x32_bf16(a, b, acc[m], 0, 0, 0);
      }
    }
    // write partial ssq for this chunk (atomics sealed by entry barrier)
    if (tid < 128) {
      sqo[s * 128 + tid] = ssq_l[s & 1][tid];
      ssq_l[s & 1][tid] = 0.f;
    }
    // write partial logits
    const int p = s * 128 + wv * 16 + l15;
    if (p < PP) {
      #pragma unroll
      for (int m = 0; m < 4; ++m)
        #pragma unroll
        for (int r = 0; r < 4; ++r) {
          const int k = 16 * m + lh * 4 + r;
          lqo[(size_t)k * PP + p] = (__bf16)acc[m][r];
        }
    }
    if (s + 1 < 8) STORE(s + 1);
    LGKM_BAR();
  }
}

// --- softmax: sum 8 partials (L3-hot), maxless softmax, write a' + asum.
//     Block (p-tile 64, n); 256 thr = 64 k x 4 p-groups of 16.  (R12-proven)
__global__ __launch_bounds__(256) void k_softmax(const __bf16* __restrict__ Lq,
                                                 const float* __restrict__ ssqq,
                                                 __bf16* __restrict__ at,
                                                 float* __restrict__ asum) {
  __shared__ float invn_l[64], invs_l[64], S_l[64], ak_l[64];
  __shared__ float Ls[64][66];
  const int n = blockIdx.y, pt = blockIdx.x;
  const int t = threadIdx.x;
  const int k = t & 63, pg = t >> 6;

  if (t < 64) {
    float ss = 0.f;
    #pragma unroll
    for (int q2 = 0; q2 < 8; ++q2)
      ss += ssqq[((size_t)(q2 * N_ + n) << 10) + pt * 64 + t];
    invn_l[t] = 1.f / fmaxf(sqrtf(ss), 1e-12f);
    S_l[t] = 0.f; ak_l[t] = 0.f;
  }
  __syncthreads();

  float L[16];
  #pragma unroll
  for (int i = 0; i < 16; ++i) L[i] = 0.f;
  const size_t QS = (size_t)N_ * K_ * PP;
  const __bf16* lb = Lq + ((size_t)n * K_ + k) * PP + pt * 64 + pg * 16;
  #pragma unroll
  for (int q2 = 0; q2 < 8; ++q2) {
    bf16x8 u0 = *reinterpret_cast<const bf16x8*>(lb + q2 * QS);
    bf16x8 u1 = *reinterpret_cast<const bf16x8*>(lb + q2 * QS + 8);
    #pragma unroll
    for (int i = 0; i < 8; ++i) { L[i] += (float)u0[i]; L[8 + i] += (float)u1[i]; }
  }
  float e[16];
  #pragma unroll
  for (int i = 0; i < 16; ++i) {
    const int p = pt * 64 + pg * 16 + i;
    e[i] = (p < P_) ? __expf(L[i] * invn_l[pg * 16 + i]) : 0.f;  // maxless
    Ls[k][pg * 16 + i] = e[i];
  }
  __syncthreads();
  {
    const int pl = t & 63, kc = t >> 6;
    float s = 0.f;
    #pragma unroll
    for (int kk = 0; kk < 16; ++kk) s += Ls[kc * 16 + kk][pl];
    atomicAdd(&S_l[pl], s);
  }
  __syncthreads();
  if (t < 64) {
    const float S = S_l[t];
    invs_l[t] = (S > 0.f) ? 1.f / S : 0.f;
  }
  __syncthreads();

  float aps = 0.f;
  bf16x8 o0, o1;
  #pragma unroll
  for (int i = 0; i < 16; ++i) {
    const float a = e[i] * invs_l[pg * 16 + i];
    aps += a;
    const float ap = a * invn_l[pg * 16 + i];
    if (i < 8) o0[i] = (__bf16)ap; else o1[i - 8] = (__bf16)ap;
  }
  __bf16* ao = at + ((size_t)n * K_ + k) * PP + pt * 64 + pg * 16;
  *reinterpret_cast<bf16x8*>(ao)     = o0;
  *reinterpret_cast<bf16x8*>(ao + 8) = o1;
  atomicAdd(&ak_l[k], aps);
  __syncthreads();
  if (t < 64) unsafeAtomicAdd(asum + n * K_ + t, ak_l[t]);
}

// --- phase 2 (unchanged): vlad[k][c] = sum_p a'[k][p]*x[c][p] - asum[k]*cent[k][c]
__global__ __launch_bounds__(256) void k_phase2(const float* __restrict__ x,
                                                const __bf16* __restrict__ at,
                                                const float* __restrict__ asum,
                                                const float* __restrict__ cent,
                                                float* __restrict__ out) {
  __shared__ __bf16 Al[2][64][40];
  __shared__ __bf16 Xl[2][64][40];
  const int n   = blockIdx.y;
  const int c0  = blockIdx.x * 64;
  const int tid = threadIdx.x;
  const int w   = tid >> 6, l = tid & 63;
  const int l15 = l & 15,  lh = l >> 4;

  const int ak  = tid >> 2, ach = tid & 3;
  const int xc  = tid >> 3, xch = tid & 7;
  const size_t abase  = ((size_t)n * K_ + ak) * PP + ach * 8;
  const size_t xbase0 = ((size_t)n * C_ + c0 + xc) * P_ + xch * 4;
  const size_t xbase1 = ((size_t)n * C_ + c0 + xc + 32) * P_ + xch * 4;

  f32x4 acc[4] = {};
  bf16x8 na; float4 v0, v1;

  auto LOAD = [&](int s) {
    na = *reinterpret_cast<const bf16x8*>(at + abase + s * 32);
    size_t o0 = xbase0 + s * 32; if (o0 > TOT_X - 4) o0 = TOT_X - 4;
    size_t o1 = xbase1 + s * 32; if (o1 > TOT_X - 4) o1 = TOT_X - 4;
    v0 = *reinterpret_cast<const float4*>(x + o0);
    v1 = *reinterpret_cast<const float4*>(x + o1);
  };
  auto STORE = [&](int b) {
    *reinterpret_cast<bf16x8*>(&Al[b][ak][ach * 8]) = na;
    bf16x4 p0 = { (__bf16)v0.x, (__bf16)v0.y, (__bf16)v0.z, (__bf16)v0.w };
    bf16x4 p1 = { (__bf16)v1.x, (__bf16)v1.y, (__bf16)v1.z, (__bf16)v1.w };
    *reinterpret_cast<bf16x4*>(&Xl[b][xc][xch * 4])      = p0;
    *reinterpret_cast<bf16x4*>(&Xl[b][xc + 32][xch * 4]) = p1;
  };

  LOAD(0); STORE(0);
  LGKM_BAR();

  #pragma unroll 2
  for (int s = 0; s < 29; ++s) {
    if (s < 28) LOAD(s + 1);
    bf16x8 b = *reinterpret_cast<const bf16x8*>(&Xl[s & 1][16 * w + l15][lh * 8]);
    #pragma unroll
    for (int m = 0; m < 4; ++m) {
      bf16x8 a = *reinterpret_cast<const bf16x8*>(&Al[s & 1][16 * m + l15][lh * 8]);
      acc[m] = __builtin_amdgcn_mfma_f32_16x16x32_bf16(a, b, acc[m], 0, 0, 0);
    }
    if (s < 28) STORE((s + 1) & 1);
    LGKM_BAR();
  }

  const int c = c0 + 16 * w + l15;
  #pragma unroll
  for (int m = 0; m < 4; ++m) {
    #pragma unroll
    for (int r = 0; r < 4; ++r) {
      const int k = 16 * m + lh * 4 + r;
      out[((size_t)n * K_ + k) * C_ + c] =
          acc[m][r] - asum[n * K_ + k] * cent[(size_t)k * C_ + c];
    }
  }
}

extern "C" void kernel_launch(void* const* d_in, const int* in_sizes, int n_in,
                              void* d_out, int out_size, void* d_ws, size_t ws_size,
                              hipStream_t stream) {
  const float* x    = (const float*)d_in[0];
  const float* w    = (const float*)d_in[1];
  const float* cent = (const float*)d_in[2];
  float* out = (float*)d_out;
  char* wsb  = (char*)d_ws;
  __bf16* at   = (__bf16*)wsb;
  float*  asum = (float*)(wsb + ASUM_OFF);
  __bf16* wbr  = (__bf16*)(wsb + WBR_OFF);
  float*  ssqq = (float*)(wsb + SSQ_OFF);
  __bf16* Lq   = (__bf16*)(wsb + LQ_OFF);

  k_prep_w<<<dim3(16), dim3(256), 0, stream>>>(w, wbr, asum);
  k_phase1<<<dim3(8, 64), dim3(512), 0, stream>>>(x, wbr, Lq, ssqq);
  k_softmax<<<dim3(15, 64), dim3(256), 0, stream>>>(Lq, ssqq, at, asum);
  k_phase2<<<dim3(8, 64), dim3(256), 0, stream>>>(x, at, asum, cent, out);
}